// Round 8
// baseline (1183.606 us; speedup 1.0000x reference)
//
#include <hip/hip_runtime.h>
#include <hip/hip_bf16.h>
#include <hip/hip_cooperative_groups.h>

namespace cg = cooperative_groups;

// FacePartGAT: dense-graph GATConv x2 + mean + fc on MI355X. ALL I/O fp32.
// e[i,j] = leaky_relu(t_i + s_j) => softmax aggregation factorizes after
// sorting sources by s_j (prefix/suffix tables + binary search). Exact.
// Round 8: ONE cooperative mega-kernel (512 blocks x 256 thr, 2 blocks/CU),
// 18 grid.sync()s replace 19 serialized graph dispatches (~3-4us gap each).

#define NNODE 4096
#define CDIM 128
#define TW 132
#define NEG 0.2f
#define CHUNK 64
#define NCHUNK 64
#define SEG 8
#define SEGK (NNODE / SEG)  // 512
#define GRID 512
#define TPB 256

typedef __bf16 bf16x8 __attribute__((ext_vector_type(8)));
typedef float f32x4 __attribute__((ext_vector_type(4)));

__device__ __forceinline__ unsigned short f2b(float f) {
  unsigned int u = __float_as_uint(f);
  u += 0x7fffu + ((u >> 16) & 1u);  // RTNE
  return (unsigned short)(u >> 16);
}

union SmemU {
  float tile[64][65];                                              // prep transpose
  struct { unsigned short As[64 * 40]; unsigned short Bs[64 * 40]; } g;  // gemm
  struct { float hrow[CHUNK][CDIM]; float eP[CHUNK]; float eM[CHUNK]; int ids[CHUNK]; } pc;
  struct { float eP[CHUNK]; float eM[CHUNK]; int ids[CHUNK]; } pa;
  float keys[SEGK];
  float red[TPB];
};

// ---- phase device functions (all guards INSIDE; grid.sync at top level) ----

__device__ void prep_dev(const float* x, const float* W1, const float* W2,
                         unsigned short* xb, unsigned short* W1t, unsigned short* W2t,
                         SmemU* sm) {
  int tid = threadIdx.x;
  int nq = NNODE * 768 / 4;
  for (int i = blockIdx.x * TPB + tid; i < nq; i += GRID * TPB) {
    float4 v = ((const float4*)x)[i];
    ushort4 o;
    o.x = f2b(v.x); o.y = f2b(v.y); o.z = f2b(v.z); o.w = f2b(v.w);
    ((ushort4*)xb)[i] = o;
  }
  int tb = blockIdx.x;
  if (tb < 96 + 16) {
    const float* W; unsigned short* Wt; int K, N, n0, k0;
    if (tb < 96) { W = W1; Wt = W1t; K = 768; N = 512; n0 = (tb & 7) * 64; k0 = (tb >> 3) * 64; }
    else { int b3 = tb - 96; W = W2; Wt = W2t; K = 512; N = 128; n0 = (b3 & 1) * 64; k0 = (b3 >> 1) * 64; }
    for (int p = 0; p < 16; p++) {
      int e = p * 256 + tid;
      int rr = e >> 6, cc = e & 63;
      sm->tile[rr][cc] = W[(size_t)(k0 + rr) * N + n0 + cc];
    }
    __syncthreads();
    for (int p = 0; p < 16; p++) {
      int e = p * 256 + tid;
      int rr = e >> 6, cc = e & 63;
      Wt[(size_t)(n0 + rr) * K + k0 + cc] = f2b(sm->tile[cc][rr]);
    }
  }
}

template <int BM, int BN>
__device__ void gemm_dev(const unsigned short* A, const unsigned short* Bt, float* C,
                         int N, int K, int bx, int by,
                         unsigned short* As, unsigned short* Bs) {
  constexpr int WM = BM / 2, WN = BN / 2;
  constexpr int FI = WM / 16, FJ = WN / 16;
  constexpr int EA = BM * 32 / 8, EB = BN * 32 / 8;
  constexpr int NA = (EA + 255) / 256, NB = (EB + 255) / 256;
  int tid = threadIdx.x;
  int lane = tid & 63, wave = tid >> 6;
  int wm = (wave >> 1) * WM, wn = (wave & 1) * WN;
  int m0 = by * BM, n0 = bx * BN;
  int fm = lane & 15, fq = lane >> 4;
  f32x4 acc[FI][FJ] = {};
  for (int k0 = 0; k0 < K; k0 += 32) {
    uint4 ar[NA], br[NB];
#pragma unroll
    for (int q = 0; q < NA; q++) {
      int e = q * 256 + tid;
      if (e < EA) {
        int r = (e * 8) >> 5, kk = (e * 8) & 31;
        ar[q] = *(const uint4*)(A + (size_t)(m0 + r) * K + k0 + kk);
      }
    }
#pragma unroll
    for (int q = 0; q < NB; q++) {
      int e = q * 256 + tid;
      if (e < EB) {
        int r = (e * 8) >> 5, kk = (e * 8) & 31;
        br[q] = *(const uint4*)(Bt + (size_t)(n0 + r) * K + k0 + kk);
      }
    }
    __syncthreads();
#pragma unroll
    for (int q = 0; q < NA; q++) {
      int e = q * 256 + tid;
      if (e < EA) {
        int r = (e * 8) >> 5, kk = (e * 8) & 31;
        *(uint4*)&As[r * 40 + kk] = ar[q];
      }
    }
#pragma unroll
    for (int q = 0; q < NB; q++) {
      int e = q * 256 + tid;
      if (e < EB) {
        int r = (e * 8) >> 5, kk = (e * 8) & 31;
        *(uint4*)&Bs[r * 40 + kk] = br[q];
      }
    }
    __syncthreads();
    bf16x8 af[FI], bfr[FJ];
#pragma unroll
    for (int i = 0; i < FI; i++)
      af[i] = *(const bf16x8*)&As[(wm + i * 16 + fm) * 40 + fq * 8];
#pragma unroll
    for (int j = 0; j < FJ; j++)
      bfr[j] = *(const bf16x8*)&Bs[(wn + j * 16 + fm) * 40 + fq * 8];
#pragma unroll
    for (int i = 0; i < FI; i++)
#pragma unroll
      for (int j = 0; j < FJ; j++)
        acc[i][j] = __builtin_amdgcn_mfma_f32_16x16x32_bf16(af[i], bfr[j], acc[i][j], 0, 0, 0);
  }
#pragma unroll
  for (int i = 0; i < FI; i++) {
#pragma unroll
    for (int j = 0; j < FJ; j++) {
      int r = m0 + wm + i * 16 + fq * 4;
      int ccol = n0 + wn + j * 16 + fm;
#pragma unroll
      for (int reg = 0; reg < 4; reg++)
        C[(size_t)(r + reg) * N + ccol] = acc[i][j][reg];
    }
  }
}

__device__ void st_dev(const float* h, const float* asrc, const float* adst,
                       float* s, float* t, int H) {
  int wave = threadIdx.x >> 6, lane = threadIdx.x & 63;
  int HC = H * CDIM;
  int nIt = NNODE * H;
  for (int item = blockIdx.x * 4 + wave; item < nIt; item += GRID * 4) {
    int n = item / H, hh = item % H;
    float2 hv = *(const float2*)&h[(size_t)n * HC + hh * CDIM + lane * 2];
    float2 av = *(const float2*)&asrc[hh * CDIM + lane * 2];
    float2 dv = *(const float2*)&adst[hh * CDIM + lane * 2];
    float ps = hv.x * av.x + hv.y * av.y;
    float pt = hv.x * dv.x + hv.y * dv.y;
#pragma unroll
    for (int o = 32; o > 0; o >>= 1) {
      ps += __shfl_down(ps, o, 64);
      pt += __shfl_down(pt, o, 64);
    }
    if (lane == 0) {
      s[(size_t)hh * NNODE + n] = ps;
      t[(size_t)hh * NNODE + n] = pt;
    }
  }
}

__device__ void rank_count_dev(const float* s, int* partial, int H, float* keys) {
  int tid = threadIdx.x;
  int nIt = H * SEG * (NNODE / 256);
  for (int it = blockIdx.x; it < nIt; it += GRID) {
    int hh = it / (SEG * 16);
    int rem = it % (SEG * 16);
    int seg = rem >> 4, mib = rem & 15;
    const float* sp = s + (size_t)hh * NNODE;
    __syncthreads();
    for (int k = tid; k < SEGK; k += 256) keys[k] = sp[seg * SEGK + k];
    __syncthreads();
    int mi = mib * 256 + tid;
    float mk = sp[mi];
    int jbase = seg * SEGK;
    int cnt = 0;
#pragma unroll 4
    for (int j = 0; j < SEGK; j += 4) {
      float4 kv = *(const float4*)&keys[j];
      int jj = jbase + j;
      cnt += (kv.x < mk) || (kv.x == mk && (jj + 0) < mi);
      cnt += (kv.y < mk) || (kv.y == mk && (jj + 1) < mi);
      cnt += (kv.z < mk) || (kv.z == mk && (jj + 2) < mi);
      cnt += (kv.w < mk) || (kv.w == mk && (jj + 3) < mi);
    }
    partial[((size_t)hh * SEG + seg) * NNODE + mi] = cnt;
  }
}

__device__ void scatter_dev(const float* s, const int* partial,
                            float* ss, int* si, int H) {
  int nIt = H * (NNODE / 256);
  for (int it = blockIdx.x; it < nIt; it += GRID) {
    int hh = it / 16, mib = it % 16;
    int mi = mib * 256 + threadIdx.x;
    int rank = 0;
#pragma unroll
    for (int g = 0; g < SEG; g++) rank += partial[((size_t)hh * SEG + g) * NNODE + mi];
    ss[(size_t)hh * NNODE + rank] = s[(size_t)hh * NNODE + mi];
    si[(size_t)hh * NNODE + rank] = mi;
  }
}

__device__ void passA_dev(const float* h, const float* ss, const int* si,
                          float* partP, float* partM, int H,
                          float* eP, float* eM, int* ids) {
  int tid = threadIdx.x;
  int HC = H * CDIM;
  int nIt = H * NCHUNK;
  for (int it = blockIdx.x; it < nIt; it += GRID) {
    int hh = it / NCHUNK, ci = it % NCHUNK;
    int base = ci * CHUNK;
    __syncthreads();
    if (tid < CHUNK) {
      float sv = ss[(size_t)hh * NNODE + base + tid];
      ids[tid] = si[(size_t)hh * NNODE + base + tid];
      eP[tid] = expf(sv);
      eM[tid] = expf(NEG * sv);
    }
    __syncthreads();
    if (tid < CDIM) {
      int c = tid;
      float sp = 0.f, smv = 0.f;
      for (int kb = 0; kb < CHUNK; kb += 8) {
        float v[8];
#pragma unroll
        for (int j = 0; j < 8; j++)
          v[j] = h[(size_t)ids[kb + j] * HC + hh * CDIM + c];
#pragma unroll
        for (int j = 0; j < 8; j++) {
          sp = fmaf(eP[kb + j], v[j], sp);
          smv = fmaf(eM[kb + j], v[j], smv);
        }
      }
      size_t o = ((size_t)hh * NCHUNK + ci) * TW;
      partP[o + c] = sp;
      partM[o + c] = smv;
      if (c == 0) {
        float zp = 0.f, zm = 0.f;
#pragma unroll
        for (int k = 0; k < CHUNK; k++) { zp += eP[k]; zm += eM[k]; }
        partP[o + 128] = zp;
        partM[o + 128] = zm;
      }
    }
  }
}

__device__ void passB_dev(const float* partP, const float* partM,
                          float* carryP, float* carryM, int H) {
  int gt = blockIdx.x * TPB + threadIdx.x;
  int nCols = H * 129;
  if (gt >= nCols) return;
  int hh = gt / 129, c = gt % 129;
  float run = 0.f;
  for (int g0 = 0; g0 < NCHUNK; g0 += 8) {
    float v[8];
#pragma unroll
    for (int j = 0; j < 8; j++) v[j] = partM[((size_t)hh * NCHUNK + g0 + j) * TW + c];
#pragma unroll
    for (int j = 0; j < 8; j++) {
      carryM[((size_t)hh * NCHUNK + g0 + j) * TW + c] = run;
      run += v[j];
    }
  }
  run = 0.f;
  for (int g0 = NCHUNK - 8; g0 >= 0; g0 -= 8) {
    float v[8];
#pragma unroll
    for (int j = 0; j < 8; j++) v[j] = partP[((size_t)hh * NCHUNK + g0 + j) * TW + c];
#pragma unroll
    for (int j = 7; j >= 0; j--) {
      carryP[((size_t)hh * NCHUNK + g0 + j) * TW + c] = run;
      run += v[j];
    }
  }
}

__device__ void passC_dev(const float* h, const float* ss, const int* si,
                          const float* carryP, const float* carryM,
                          float* SSt, float* PPt, int H,
                          float (*hrow)[CDIM], float* eP, float* eM, int* ids) {
  int tid = threadIdx.x;
  int HC = H * CDIM;
  int nIt = H * NCHUNK;
  for (int it = blockIdx.x; it < nIt; it += GRID) {
    int hh = it / NCHUNK, ci = it % NCHUNK;
    int base = ci * CHUNK;
    size_t hb = (size_t)hh * (NNODE + 1);
    __syncthreads();
    if (tid < CHUNK) {
      float sv = ss[(size_t)hh * NNODE + base + tid];
      ids[tid] = si[(size_t)hh * NNODE + base + tid];
      eP[tid] = expf(sv);
      eM[tid] = expf(NEG * sv);
    }
    __syncthreads();
    if (tid < CDIM) {
      int c = tid;
      for (int kb = 0; kb < CHUNK; kb += 8) {
        float v[8];
#pragma unroll
        for (int j = 0; j < 8; j++)
          v[j] = h[(size_t)ids[kb + j] * HC + hh * CDIM + c];
#pragma unroll
        for (int j = 0; j < 8; j++) hrow[kb + j][c] = v[j];
      }
      size_t co = ((size_t)hh * NCHUNK + ci) * TW;
      float runm = carryM[co + c], runzm = carryM[co + 128];
#pragma unroll 8
      for (int k = 0; k < CHUNK; k++) {
        size_t row = (hb + base + k) * TW;
        PPt[row + c] = runm;
        if (c == 0) PPt[row + 128] = runzm;
        runm = fmaf(eM[k], hrow[k][c], runm);
        runzm += eM[k];
      }
      if (ci == NCHUNK - 1) {
        size_t row = (hb + NNODE) * TW;
        PPt[row + c] = runm;
        if (c == 0) PPt[row + 128] = runzm;
      }
      float runp = carryP[co + c], runzp = carryP[co + 128];
#pragma unroll 8
      for (int k = CHUNK - 1; k >= 0; k--) {
        runp = fmaf(eP[k], hrow[k][c], runp);
        runzp += eP[k];
        size_t row = (hb + base + k) * TW;
        SSt[row + c] = runp;
        if (c == 0) SSt[row + 128] = runzp;
      }
      if (ci == NCHUNK - 1) {
        size_t row = (hb + NNODE) * TW;
        SSt[row + c] = 0.f;
        if (c == 0) SSt[row + 128] = 0.f;
      }
    }
  }
}

template <bool BF16OUT>
__device__ void attend_dev(const float* SSt, const float* PPt, const float* ss,
                           const float* tt, const float* bias, void* outp, int H) {
  int half = threadIdx.x >> 7, c = threadIdx.x & 127;
  int nIt = NNODE * H;
  for (int b = blockIdx.x * 2 + half; b < nIt; b += GRID * 2) {
    int n = b / H, hh = b % H;
    float tv = tt[(size_t)hh * NNODE + n];
    const float* sp = ss + (size_t)hh * NNODE;
    float thr = -tv;
    int lo = 0, hi = NNODE;
    while (lo < hi) { int mid = (lo + hi) >> 1; if (sp[mid] < thr) lo = mid + 1; else hi = mid; }
    size_t hb = (size_t)hh * (NNODE + 1);
    float wp = expf(tv), wm = expf(NEG * tv);
    float num = wp * SSt[(hb + lo) * TW + c] + wm * PPt[(hb + lo) * TW + c];
    float Z = wp * SSt[(hb + lo) * TW + 128] + wm * PPt[(hb + lo) * TW + 128];
    float o = num / Z + bias[hh * CDIM + c];
    float r = (o > 0.f) ? o : (expf(o) - 1.f);
    if constexpr (BF16OUT)
      ((unsigned short*)outp)[(size_t)n * (H * CDIM) + hh * CDIM + c] = f2b(r);
    else
      ((float*)outp)[(size_t)n * (H * CDIM) + hh * CDIM + c] = r;
  }
}

__device__ void mean_dev(const float* x3, float* mv, float* red) {
  if (blockIdx.x >= CDIM) return;
  int c = blockIdx.x, tid = threadIdx.x;
  float acc = 0.f;
  for (int i = tid; i < NNODE; i += TPB) acc += x3[(size_t)i * CDIM + c];
  red[tid] = acc; __syncthreads();
  for (int o = 128; o > 0; o >>= 1) { if (tid < o) red[tid] += red[tid + o]; __syncthreads(); }
  if (tid == 0) mv[c] = red[0] * (1.f / NNODE);
}

__device__ void fc_dev(const float* mv, const float* fcW, const float* fcb, float* out) {
  int d = blockIdx.x * TPB + threadIdx.x;
  if (d >= 768) return;
  float acc = fcb[d];
  for (int c2 = 0; c2 < CDIM; c2++) acc = fmaf(mv[c2], fcW[c2 * 768 + d], acc);
  out[d] = acc;
}

// ---- the mega kernel ----
__global__ __launch_bounds__(TPB, 2) void mega_kernel(
    const float* x, const float* W1, const float* as1, const float* ad1, const float* b1,
    const float* W2, const float* as2, const float* ad2, const float* b2,
    const float* fcW, const float* fcb, float* ws, float* out) {
  cg::grid_group grid = cg::this_grid();
  __shared__ __align__(16) SmemU sm;

  size_t off = 0;
  auto alloc = [&](size_t n) { float* p = ws + off; off += n; return p; };
  float* h1  = alloc((size_t)NNODE * 512);
  float* x2f = alloc((size_t)NNODE * 512);
  float* h2  = alloc((size_t)NNODE * 128);
  float* x3  = alloc((size_t)NNODE * 128);
  float* s1  = alloc((size_t)4 * NNODE);
  float* t1  = alloc((size_t)4 * NNODE);
  float* sS1 = alloc((size_t)4 * NNODE);
  int*   sI1 = (int*)alloc((size_t)4 * NNODE);
  float* SS1 = alloc((size_t)4 * (NNODE + 1) * TW);
  float* PP1 = alloc((size_t)4 * (NNODE + 1) * TW);
  float* pP1 = alloc((size_t)4 * NCHUNK * TW);
  float* pM1 = alloc((size_t)4 * NCHUNK * TW);
  float* cP1 = alloc((size_t)4 * NCHUNK * TW);
  float* cM1 = alloc((size_t)4 * NCHUNK * TW);
  float* s2  = alloc(NNODE);
  float* t2  = alloc(NNODE);
  float* sS2 = alloc(NNODE);
  int*   sI2 = (int*)alloc(NNODE);
  float* SS2 = alloc((size_t)(NNODE + 1) * TW);
  float* PP2 = alloc((size_t)(NNODE + 1) * TW);
  float* pP2 = alloc((size_t)NCHUNK * TW);
  float* pM2 = alloc((size_t)NCHUNK * TW);
  float* cP2 = alloc((size_t)NCHUNK * TW);
  float* cM2 = alloc((size_t)NCHUNK * TW);
  float* mv  = alloc(128);
  int*   rparts = (int*)alloc((size_t)4 * SEG * NNODE);

  unsigned short* xb  = (unsigned short*)PP1;   // phases 0-1 only; PP1 written phase 7
  unsigned short* W1t = (unsigned short*)SS1;   // phases 0-1 only; SS1 written phase 7
  unsigned short* x2b = (unsigned short*)x2f;
  unsigned short* W2t = (unsigned short*)(x2f + NNODE * 256 + 64);

  // 0: prep
  prep_dev(x, W1, W2, xb, W1t, W2t, &sm);
  grid.sync();
  // 1: GEMM1 — 512 tiles of 64x64 map 1:1 onto the grid
  gemm_dev<64, 64>(xb, W1t, h1, 512, 768, blockIdx.x % 8, blockIdx.x / 8,
                   sm.g.As, sm.g.Bs);
  grid.sync();
  // 2-8: layer-1 attention
  st_dev(h1, as1, ad1, s1, t1, 4);
  grid.sync();
  rank_count_dev(s1, rparts, 4, sm.keys);
  grid.sync();
  scatter_dev(s1, rparts, sS1, sI1, 4);
  grid.sync();
  passA_dev(h1, sS1, sI1, pP1, pM1, 4, sm.pa.eP, sm.pa.eM, sm.pa.ids);
  grid.sync();
  passB_dev(pP1, pM1, cP1, cM1, 4);
  grid.sync();
  passC_dev(h1, sS1, sI1, cP1, cM1, SS1, PP1, 4, sm.pc.hrow, sm.pc.eP, sm.pc.eM, sm.pc.ids);
  grid.sync();
  attend_dev<true>(SS1, PP1, sS1, t1, b1, x2b, 4);
  grid.sync();
  // 9: GEMM2 — 256 tiles of 32x64
  if (blockIdx.x < 256)
    gemm_dev<32, 64>(x2b, W2t, h2, 128, 512, blockIdx.x & 1, blockIdx.x >> 1,
                     sm.g.As, sm.g.Bs);
  grid.sync();
  // 10-16: layer-2 attention
  st_dev(h2, as2, ad2, s2, t2, 1);
  grid.sync();
  rank_count_dev(s2, rparts, 1, sm.keys);
  grid.sync();
  scatter_dev(s2, rparts, sS2, sI2, 1);
  grid.sync();
  passA_dev(h2, sS2, sI2, pP2, pM2, 1, sm.pa.eP, sm.pa.eM, sm.pa.ids);
  grid.sync();
  passB_dev(pP2, pM2, cP2, cM2, 1);
  grid.sync();
  passC_dev(h2, sS2, sI2, cP2, cM2, SS2, PP2, 1, sm.pc.hrow, sm.pc.eP, sm.pc.eM, sm.pc.ids);
  grid.sync();
  attend_dev<false>(SS2, PP2, sS2, t2, b2, x3, 1);
  grid.sync();
  // 17-18: readout
  mean_dev(x3, mv, sm.red);
  grid.sync();
  fc_dev(mv, fcW, fcb, out);
}

extern "C" void kernel_launch(void* const* d_in, const int* in_sizes, int n_in,
                              void* d_out, int out_size, void* d_ws, size_t ws_size,
                              hipStream_t stream) {
  const float* x   = (const float*)d_in[0];
  const float* W1  = (const float*)d_in[1];
  const float* as1 = (const float*)d_in[2];
  const float* ad1 = (const float*)d_in[3];
  const float* b1  = (const float*)d_in[4];
  const float* W2  = (const float*)d_in[5];
  const float* as2 = (const float*)d_in[6];
  const float* ad2 = (const float*)d_in[7];
  const float* b2  = (const float*)d_in[8];
  const float* fcW = (const float*)d_in[9];
  const float* fcb = (const float*)d_in[10];
  float* wsf = (float*)d_ws;
  float* outp = (float*)d_out;

  void* args[13] = {
    (void*)&x, (void*)&W1, (void*)&as1, (void*)&ad1, (void*)&b1,
    (void*)&W2, (void*)&as2, (void*)&ad2, (void*)&b2,
    (void*)&fcW, (void*)&fcb, (void*)&wsf, (void*)&outp
  };
  hipLaunchCooperativeKernel((void*)mega_kernel, dim3(GRID), dim3(TPB), args, 0, stream);
}

// Round 9
// 412.861 us; speedup vs baseline: 2.8668x; 2.8668x over previous
//
#include <hip/hip_runtime.h>
#include <hip/hip_bf16.h>

// FacePartGAT: dense-graph GATConv x2 + mean + fc on MI355X. ALL I/O fp32.
// e[i,j] = leaky_relu(t_i + s_j) => softmax aggregation factorizes after
// sorting sources by s_j (prefix/suffix tables + binary search). Exact.
// Round 9: revert cooperative (grid.sync ~60us each on gfx950 — 8 XCD
// coherence). Keep 19-dispatch r7 structure but cut to 14 barrier-free:
//  - prep dropped: GEMMs convert fp32->bf16 during LDS staging (B transposed
//    on write from native [K,N] layout)
//  - rank_count+scatter -> single sort dispatch (4096 keys fit in 16KB LDS)
//  - passB fused into passC with BATCHED carry loads (16 in flight)

#define NNODE 4096
#define CDIM 128
#define TW 132           // table width: 128 features + z at col 128
#define NEG 0.2f
#define CHUNK 64
#define NCHUNK 64        // NNODE / CHUNK

typedef __bf16 bf16x8 __attribute__((ext_vector_type(8)));
typedef float f32x4 __attribute__((ext_vector_type(4)));

__device__ __forceinline__ unsigned short f2b(float f) {
  unsigned int u = __float_as_uint(f);
  u += 0x7fffu + ((u >> 16) & 1u);  // RTNE
  return (unsigned short)(u >> 16);
}
__device__ __forceinline__ unsigned int pack2(float a, float b) {
  return (unsigned int)f2b(a) | ((unsigned int)f2b(b) << 16);
}

// C[M,N] = A[M,K] x B[K,N]. A fp32 or bf16 (row-major, K-contig);
// B fp32 in native [K,N] layout, transposed+converted during staging.
// BK=32, 256 thr = 4 waves (2x2), wave tile WM=BM/2, WN=BN/2.
template <int BM, int BN, bool A_BF16>
__global__ __launch_bounds__(256) void mfma_gemm(const void* __restrict__ Ap,
                                                 const float* __restrict__ B,
                                                 float* __restrict__ C,
                                                 int M, int N, int K) {
  __shared__ __align__(16) unsigned short As[BM * 40];
  __shared__ __align__(16) unsigned short Bs[BN * 40];
  constexpr int WM = BM / 2, WN = BN / 2;
  constexpr int FI = WM / 16, FJ = WN / 16;
  constexpr int EA = BM * 32 / 8;          // 8-elem groups for A
  constexpr int NA = (EA + 255) / 256;
  constexpr int EBF = 32 * BN / 4;         // float4 groups for B (per k-row: BN/4)
  constexpr int NBF = (EBF + 255) / 256;
  int tid = threadIdx.x;
  int lane = tid & 63, wave = tid >> 6;
  int wm = (wave >> 1) * WM, wn = (wave & 1) * WN;
  int m0 = blockIdx.y * BM, n0 = blockIdx.x * BN;
  int fm = lane & 15, fq = lane >> 4;
  f32x4 acc[FI][FJ] = {};
  for (int k0 = 0; k0 < K; k0 += 32) {
    uint4 ar[NA];
    float4 bw[NBF];
#pragma unroll
    for (int q = 0; q < NA; q++) {
      int e = q * 256 + tid;
      if (e < EA) {
        int r = e >> 2, kk = (e & 3) * 8;
        if constexpr (A_BF16) {
          ar[q] = *(const uint4*)((const unsigned short*)Ap + (size_t)(m0 + r) * K + k0 + kk);
        } else {
          const float4* pa = (const float4*)((const float*)Ap + (size_t)(m0 + r) * K + k0 + kk);
          float4 f0 = pa[0], f1 = pa[1];
          ar[q].x = pack2(f0.x, f0.y); ar[q].y = pack2(f0.z, f0.w);
          ar[q].z = pack2(f1.x, f1.y); ar[q].w = pack2(f1.z, f1.w);
        }
      }
    }
#pragma unroll
    for (int q = 0; q < NBF; q++) {
      int e = q * 256 + tid;
      if (e < EBF) {
        int kk = e / (BN / 4), n4 = e % (BN / 4);
        bw[q] = *(const float4*)(B + (size_t)(k0 + kk) * N + n0 + n4 * 4);
      }
    }
    __syncthreads();
#pragma unroll
    for (int q = 0; q < NA; q++) {
      int e = q * 256 + tid;
      if (e < EA) {
        int r = e >> 2, kk = (e & 3) * 8;
        *(uint4*)&As[r * 40 + kk] = ar[q];
      }
    }
#pragma unroll
    for (int q = 0; q < NBF; q++) {
      int e = q * 256 + tid;
      if (e < EBF) {
        int kk = e / (BN / 4), n4 = e % (BN / 4);
        Bs[(n4 * 4 + 0) * 40 + kk] = f2b(bw[q].x);
        Bs[(n4 * 4 + 1) * 40 + kk] = f2b(bw[q].y);
        Bs[(n4 * 4 + 2) * 40 + kk] = f2b(bw[q].z);
        Bs[(n4 * 4 + 3) * 40 + kk] = f2b(bw[q].w);
      }
    }
    __syncthreads();
    bf16x8 af[FI], bfr[FJ];
#pragma unroll
    for (int i = 0; i < FI; i++)
      af[i] = *(const bf16x8*)&As[(wm + i * 16 + fm) * 40 + fq * 8];
#pragma unroll
    for (int j = 0; j < FJ; j++)
      bfr[j] = *(const bf16x8*)&Bs[(wn + j * 16 + fm) * 40 + fq * 8];
#pragma unroll
    for (int i = 0; i < FI; i++)
#pragma unroll
      for (int j = 0; j < FJ; j++)
        acc[i][j] = __builtin_amdgcn_mfma_f32_16x16x32_bf16(af[i], bfr[j], acc[i][j], 0, 0, 0);
  }
#pragma unroll
  for (int i = 0; i < FI; i++) {
#pragma unroll
    for (int j = 0; j < FJ; j++) {
      int r = m0 + wm + i * 16 + fq * 4;
      int ccol = n0 + wn + j * 16 + fm;
#pragma unroll
      for (int reg = 0; reg < 4; reg++)
        C[(size_t)(r + reg) * N + ccol] = acc[i][j][reg];
    }
  }
}

// s[h][n], t[h][n] via one wave per (node, head); shuffle reduce, no LDS.
__global__ void st_kernel(const float* __restrict__ h,
                          const float* __restrict__ asrc,
                          const float* __restrict__ adst,
                          float* __restrict__ s, float* __restrict__ t, int H) {
  int n = blockIdx.x;
  int wave = threadIdx.x >> 6, lane = threadIdx.x & 63;
  int HC = H * CDIM;
  float2 hv = *(const float2*)&h[(size_t)n * HC + wave * CDIM + lane * 2];
  float2 av = *(const float2*)&asrc[wave * CDIM + lane * 2];
  float2 dv = *(const float2*)&adst[wave * CDIM + lane * 2];
  float ps = hv.x * av.x + hv.y * av.y;
  float pt = hv.x * dv.x + hv.y * dv.y;
#pragma unroll
  for (int o = 32; o > 0; o >>= 1) {
    ps += __shfl_down(ps, o, 64);
    pt += __shfl_down(pt, o, 64);
  }
  if (lane == 0) {
    s[(size_t)wave * NNODE + n] = ps;
    t[(size_t)wave * NNODE + n] = pt;
  }
}

// Full rank sort in ONE dispatch: all 4096 keys of a head staged in LDS,
// each thread computes the complete rank of its key, scatters key+idx.
// rank_i = #{j: kj<ki || (kj==ki && j<i)} — exact permutation.
__global__ __launch_bounds__(256) void sort_kernel(const float* __restrict__ s,
                                                   float* __restrict__ ss,
                                                   int* __restrict__ si) {
  __shared__ __align__(16) float keys[NNODE];
  int hh = blockIdx.y, mib = blockIdx.x, tid = threadIdx.x;
  const float* sp = s + (size_t)hh * NNODE;
  for (int k4 = tid; k4 < NNODE / 4; k4 += 256)
    ((float4*)keys)[k4] = ((const float4*)sp)[k4];
  __syncthreads();
  int mi = mib * 256 + tid;
  float mk = keys[mi];
  int cnt = 0;
#pragma unroll 4
  for (int j = 0; j < NNODE; j += 4) {
    float4 kv = *(const float4*)&keys[j];
    cnt += (kv.x < mk) || (kv.x == mk && (j + 0) < mi);
    cnt += (kv.y < mk) || (kv.y == mk && (j + 1) < mi);
    cnt += (kv.z < mk) || (kv.z == mk && (j + 2) < mi);
    cnt += (kv.w < mk) || (kv.w == mk && (j + 3) < mi);
  }
  ss[(size_t)hh * NNODE + cnt] = mk;
  si[(size_t)hh * NNODE + cnt] = mi;
}

// Pass A: per-chunk partial sums of e^{s}*h (P) and e^{0.2s}*h (M); z at 128.
__global__ __launch_bounds__(128) void passA_kernel(const float* __restrict__ h,
                                                    const float* __restrict__ ss,
                                                    const int* __restrict__ si,
                                                    float* __restrict__ partP,
                                                    float* __restrict__ partM, int H) {
  __shared__ float eP[CHUNK], eM[CHUNK];
  __shared__ int ids[CHUNK];
  int b = blockIdx.x, hh = b / NCHUNK, ci = b % NCHUNK;
  int c = threadIdx.x;
  int HC = H * CDIM;
  int base = ci * CHUNK;
  if (c < CHUNK) {
    float sv = ss[(size_t)hh * NNODE + base + c];
    ids[c] = si[(size_t)hh * NNODE + base + c];
    eP[c] = expf(sv);
    eM[c] = expf(NEG * sv);
  }
  __syncthreads();
  float sp = 0.f, sm = 0.f;
  for (int kb = 0; kb < CHUNK; kb += 8) {
    float v[8];
#pragma unroll
    for (int j = 0; j < 8; j++)
      v[j] = h[(size_t)ids[kb + j] * HC + hh * CDIM + c];
#pragma unroll
    for (int j = 0; j < 8; j++) {
      sp = fmaf(eP[kb + j], v[j], sp);
      sm = fmaf(eM[kb + j], v[j], sm);
    }
  }
  size_t o = ((size_t)hh * NCHUNK + ci) * TW;
  partP[o + c] = sp;
  partM[o + c] = sm;
  if (c == 0) {
    float zp = 0.f, zm = 0.f;
#pragma unroll
    for (int k = 0; k < CHUNK; k++) { zp += eP[k]; zm += eM[k]; }
    partP[o + 128] = zp;
    partM[o + 128] = zm;
  }
}

// Pass C with fused BATCHED carry combine (16 independent loads in flight per
// batch — round 5's regression was a serial per-element walk). Then LDS-staged
// gather + dual scan, z at col 128.
__global__ __launch_bounds__(128) void passC_kernel(const float* __restrict__ h,
                                                    const float* __restrict__ ss,
                                                    const int* __restrict__ si,
                                                    const float* __restrict__ partP,
                                                    const float* __restrict__ partM,
                                                    float* __restrict__ SS,
                                                    float* __restrict__ PP, int H) {
  __shared__ float hrow[CHUNK][CDIM];  // 32 KB
  __shared__ float eP[CHUNK], eM[CHUNK];
  __shared__ int ids[CHUNK];
  int b = blockIdx.x, hh = b / NCHUNK, ci = b % NCHUNK;
  int c = threadIdx.x;
  int HC = H * CDIM;
  int base = ci * CHUNK;
  size_t hb = (size_t)hh * (NNODE + 1);
  if (c < CHUNK) {
    float sv = ss[(size_t)hh * NNODE + base + c];
    ids[c] = si[(size_t)hh * NNODE + base + c];
    eP[c] = expf(sv);
    eM[c] = expf(NEG * sv);
  }
  __syncthreads();
  // carry combine: feature columns (all threads)
  float cm = 0.f, cp = 0.f;
  for (int g0 = 0; g0 < NCHUNK; g0 += 16) {
    float vm[16], vp[16];
#pragma unroll
    for (int j = 0; j < 16; j++) {
      size_t o = ((size_t)hh * NCHUNK + g0 + j) * TW + c;
      vm[j] = partM[o];
      vp[j] = partP[o];
    }
#pragma unroll
    for (int j = 0; j < 16; j++) {
      if (g0 + j < ci) cm += vm[j];
      if (g0 + j > ci) cp += vp[j];
    }
  }
  // z carries (thread 0 only; 16-wide batches keep loads in flight)
  float zcm = 0.f, zcp = 0.f;
  if (c == 0) {
    for (int g0 = 0; g0 < NCHUNK; g0 += 16) {
      float vm[16], vp[16];
#pragma unroll
      for (int j = 0; j < 16; j++) {
        size_t o = ((size_t)hh * NCHUNK + g0 + j) * TW + 128;
        vm[j] = partM[o];
        vp[j] = partP[o];
      }
#pragma unroll
      for (int j = 0; j < 16; j++) {
        if (g0 + j < ci) zcm += vm[j];
        if (g0 + j > ci) zcp += vp[j];
      }
    }
  }
  // gather h rows once into LDS (batched, per-thread column)
  for (int kb = 0; kb < CHUNK; kb += 8) {
    float v[8];
#pragma unroll
    for (int j = 0; j < 8; j++)
      v[j] = h[(size_t)ids[kb + j] * HC + hh * CDIM + c];
#pragma unroll
    for (int j = 0; j < 8; j++) hrow[kb + j][c] = v[j];
  }
  float runm = cm, runzm = zcm;
#pragma unroll 8
  for (int k = 0; k < CHUNK; k++) {
    size_t row = (hb + base + k) * TW;
    PP[row + c] = runm;
    if (c == 0) PP[row + 128] = runzm;
    runm = fmaf(eM[k], hrow[k][c], runm);
    runzm += eM[k];
  }
  if (ci == NCHUNK - 1) {
    size_t row = (hb + NNODE) * TW;
    PP[row + c] = runm;
    if (c == 0) PP[row + 128] = runzm;
  }
  float runp = cp, runzp = zcp;
#pragma unroll 8
  for (int k = CHUNK - 1; k >= 0; k--) {
    runp = fmaf(eP[k], hrow[k][c], runp);
    runzp += eP[k];
    size_t row = (hb + base + k) * TW;
    SS[row + c] = runp;
    if (c == 0) SS[row + 128] = runzp;
  }
  if (ci == NCHUNK - 1) {
    size_t row = (hb + NNODE) * TW;
    SS[row + c] = 0.f;
    if (c == 0) SS[row + 128] = 0.f;
  }
}

// Per (dest, head): binary search split point, combine tables, +bias, ELU.
template <typename OUT>
__global__ __launch_bounds__(128) void attend_kernel(const float* __restrict__ SS,
                                                     const float* __restrict__ PP,
                                                     const float* __restrict__ ss,
                                                     const float* __restrict__ tt,
                                                     const float* __restrict__ bias,
                                                     OUT* __restrict__ out, int H) {
  int b = blockIdx.x;
  int n = b / H, hh = b % H;
  int c = threadIdx.x;
  float tv = tt[(size_t)hh * NNODE + n];
  const float* sp = ss + (size_t)hh * NNODE;
  float thr = -tv;
  int lo = 0, hi = NNODE;
  while (lo < hi) { int mid = (lo + hi) >> 1; if (sp[mid] < thr) lo = mid + 1; else hi = mid; }
  size_t hb = (size_t)hh * (NNODE + 1);
  float wp = expf(tv), wm = expf(NEG * tv);
  float num = wp * SS[(hb + lo) * TW + c] + wm * PP[(hb + lo) * TW + c];
  float Z = wp * SS[(hb + lo) * TW + 128] + wm * PP[(hb + lo) * TW + 128];
  float o = num / Z + bias[hh * CDIM + c];
  float r = (o > 0.f) ? o : (expf(o) - 1.f);
  if constexpr (sizeof(OUT) == 2)
    out[(size_t)n * (H * CDIM) + hh * CDIM + c] = f2b(r);
  else
    out[(size_t)n * (H * CDIM) + hh * CDIM + c] = r;
}

__global__ __launch_bounds__(256) void mean_kernel(const float* __restrict__ x,
                                                   float* __restrict__ m) {
  __shared__ float red[256];
  int c = blockIdx.x, tid = threadIdx.x;
  float acc = 0.f;
  for (int i = tid; i < NNODE; i += 256) acc += x[(size_t)i * CDIM + c];
  red[tid] = acc; __syncthreads();
  for (int o = 128; o > 0; o >>= 1) { if (tid < o) red[tid] += red[tid + o]; __syncthreads(); }
  if (tid == 0) m[c] = red[0] * (1.f / NNODE);
}

__global__ __launch_bounds__(256) void fc_kernel(const float* __restrict__ m,
                                                 const float* __restrict__ fcW,
                                                 const float* __restrict__ fcb,
                                                 float* __restrict__ out) {
  int d = blockIdx.x * 256 + threadIdx.x;  // 768 total
  float acc = fcb[d];
  for (int c2 = 0; c2 < CDIM; c2++) acc = fmaf(m[c2], fcW[c2 * 768 + d], acc);
  out[d] = acc;
}

extern "C" void kernel_launch(void* const* d_in, const int* in_sizes, int n_in,
                              void* d_out, int out_size, void* d_ws, size_t ws_size,
                              hipStream_t stream) {
  const float* x   = (const float*)d_in[0];
  const float* W1  = (const float*)d_in[1];
  const float* as1 = (const float*)d_in[2];
  const float* ad1 = (const float*)d_in[3];
  const float* b1  = (const float*)d_in[4];
  const float* W2  = (const float*)d_in[5];
  const float* as2 = (const float*)d_in[6];
  const float* ad2 = (const float*)d_in[7];
  const float* b2  = (const float*)d_in[8];
  const float* fcW = (const float*)d_in[9];
  const float* fcb = (const float*)d_in[10];

  float* ws = (float*)d_ws;
  size_t off = 0;
  auto alloc = [&](size_t nfloats) { float* p = ws + off; off += nfloats; return p; };

  float* h1  = alloc((size_t)NNODE * 512);
  float* x2f = alloc((size_t)NNODE * 256);   // x2b bf16 [4096,512]
  float* h2  = alloc((size_t)NNODE * 128);
  float* x3  = alloc((size_t)NNODE * 128);
  float* s1  = alloc((size_t)4 * NNODE);
  float* t1  = alloc((size_t)4 * NNODE);
  float* sS1 = alloc((size_t)4 * NNODE);
  int*   sI1 = (int*)alloc((size_t)4 * NNODE);
  float* SS1 = alloc((size_t)4 * (NNODE + 1) * TW);
  float* PP1 = alloc((size_t)4 * (NNODE + 1) * TW);
  float* pP1 = alloc((size_t)4 * NCHUNK * TW);
  float* pM1 = alloc((size_t)4 * NCHUNK * TW);
  float* s2  = alloc(NNODE);
  float* t2  = alloc(NNODE);
  float* sS2 = alloc(NNODE);
  int*   sI2 = (int*)alloc(NNODE);
  float* SS2 = alloc((size_t)(NNODE + 1) * TW);
  float* PP2 = alloc((size_t)(NNODE + 1) * TW);
  float* pP2 = alloc((size_t)NCHUNK * TW);
  float* pM2 = alloc((size_t)NCHUNK * TW);
  float* mv  = alloc(128);

  unsigned short* x2b = (unsigned short*)x2f;

  // Layer 1: GEMM converts x (fp32) and W1 (fp32, [K,N]) on the fly
  mfma_gemm<64, 64, false><<<dim3(512 / 64, NNODE / 64), 256, 0, stream>>>(x, W1, h1, NNODE, 512, 768);
  st_kernel<<<NNODE, 4 * 64, 0, stream>>>(h1, as1, ad1, s1, t1, 4);
  sort_kernel<<<dim3(NNODE / 256, 4), 256, 0, stream>>>(s1, sS1, sI1);
  passA_kernel<<<4 * NCHUNK, 128, 0, stream>>>(h1, sS1, sI1, pP1, pM1, 4);
  passC_kernel<<<4 * NCHUNK, 128, 0, stream>>>(h1, sS1, sI1, pP1, pM1, SS1, PP1, 4);
  attend_kernel<unsigned short><<<NNODE * 4, 128, 0, stream>>>(SS1, PP1, sS1, t1, b1, x2b, 4);
  // Layer 2: A = x2b bf16, B = W2 fp32 [512,128] converted on the fly
  mfma_gemm<32, 64, true><<<dim3(128 / 64, NNODE / 32), 256, 0, stream>>>(x2b, W2, h2, NNODE, 128, 512);
  st_kernel<<<NNODE, 1 * 64, 0, stream>>>(h2, as2, ad2, s2, t2, 1);
  sort_kernel<<<dim3(NNODE / 256, 1), 256, 0, stream>>>(s2, sS2, sI2);
  passA_kernel<<<NCHUNK, 128, 0, stream>>>(h2, sS2, sI2, pP2, pM2, 1);
  passC_kernel<<<NCHUNK, 128, 0, stream>>>(h2, sS2, sI2, pP2, pM2, SS2, PP2, 1);
  attend_kernel<float><<<NNODE, 128, 0, stream>>>(SS2, PP2, sS2, t2, b2, x3, 1);
  // Readout
  mean_kernel<<<128, 256, 0, stream>>>(x3, mv);
  fc_kernel<<<3, 256, 0, stream>>>(mv, fcW, fcb, (float*)d_out);
}

// Round 10
// 253.083 us; speedup vs baseline: 4.6767x; 1.6313x over previous
//
#include <hip/hip_runtime.h>
#include <hip/hip_bf16.h>

// FacePartGAT: dense-graph GATConv x2 + mean + fc on MI355X. ALL I/O fp32.
// e[i,j] = leaky_relu(t_i + s_j) => softmax aggregation factorizes after
// sorting sources by s_j (prefix/suffix tables + binary search). Exact.
// Round 10: recombine proven-best parts. Keep r9's GEMM-fused fp32->bf16
// conversion (no prep) and batched passB-in-passC fusion; RESTORE r7's
// segmented rank sort (512/128 blocks — r9's 1-dispatch sort collapsed to
// 64/16 blocks, 100us each at 2.8% occupancy).

#define NNODE 4096
#define CDIM 128
#define TW 132           // table width: 128 features + z at col 128
#define NEG 0.2f
#define CHUNK 64
#define NCHUNK 64        // NNODE / CHUNK
#define SEG 8
#define SEGK (NNODE / SEG)  // 512

typedef __bf16 bf16x8 __attribute__((ext_vector_type(8)));
typedef float f32x4 __attribute__((ext_vector_type(4)));

__device__ __forceinline__ unsigned short f2b(float f) {
  unsigned int u = __float_as_uint(f);
  u += 0x7fffu + ((u >> 16) & 1u);  // RTNE
  return (unsigned short)(u >> 16);
}
__device__ __forceinline__ unsigned int pack2(float a, float b) {
  return (unsigned int)f2b(a) | ((unsigned int)f2b(b) << 16);
}

// C[M,N] = A[M,K] x B[K,N]. A fp32 or bf16 (row-major, K-contig);
// B fp32 in native [K,N] layout, transposed+converted during staging.
// BK=32, 256 thr = 4 waves (2x2), wave tile WM=BM/2, WN=BN/2.
template <int BM, int BN, bool A_BF16>
__global__ __launch_bounds__(256) void mfma_gemm(const void* __restrict__ Ap,
                                                 const float* __restrict__ B,
                                                 float* __restrict__ C,
                                                 int M, int N, int K) {
  __shared__ __align__(16) unsigned short As[BM * 40];
  __shared__ __align__(16) unsigned short Bs[BN * 40];
  constexpr int WM = BM / 2, WN = BN / 2;
  constexpr int FI = WM / 16, FJ = WN / 16;
  constexpr int EA = BM * 32 / 8;          // 8-elem groups for A
  constexpr int NA = (EA + 255) / 256;
  constexpr int EBF = 32 * BN / 4;         // float4 groups for B (per k-row: BN/4)
  constexpr int NBF = (EBF + 255) / 256;
  int tid = threadIdx.x;
  int lane = tid & 63, wave = tid >> 6;
  int wm = (wave >> 1) * WM, wn = (wave & 1) * WN;
  int m0 = blockIdx.y * BM, n0 = blockIdx.x * BN;
  int fm = lane & 15, fq = lane >> 4;
  f32x4 acc[FI][FJ] = {};
  for (int k0 = 0; k0 < K; k0 += 32) {
    uint4 ar[NA];
    float4 bw[NBF];
#pragma unroll
    for (int q = 0; q < NA; q++) {
      int e = q * 256 + tid;
      if (e < EA) {
        int r = e >> 2, kk = (e & 3) * 8;
        if constexpr (A_BF16) {
          ar[q] = *(const uint4*)((const unsigned short*)Ap + (size_t)(m0 + r) * K + k0 + kk);
        } else {
          const float4* pa = (const float4*)((const float*)Ap + (size_t)(m0 + r) * K + k0 + kk);
          float4 f0 = pa[0], f1 = pa[1];
          ar[q].x = pack2(f0.x, f0.y); ar[q].y = pack2(f0.z, f0.w);
          ar[q].z = pack2(f1.x, f1.y); ar[q].w = pack2(f1.z, f1.w);
        }
      }
    }
#pragma unroll
    for (int q = 0; q < NBF; q++) {
      int e = q * 256 + tid;
      if (e < EBF) {
        int kk = e / (BN / 4), n4 = e % (BN / 4);
        bw[q] = *(const float4*)(B + (size_t)(k0 + kk) * N + n0 + n4 * 4);
      }
    }
    __syncthreads();
#pragma unroll
    for (int q = 0; q < NA; q++) {
      int e = q * 256 + tid;
      if (e < EA) {
        int r = e >> 2, kk = (e & 3) * 8;
        *(uint4*)&As[r * 40 + kk] = ar[q];
      }
    }
#pragma unroll
    for (int q = 0; q < NBF; q++) {
      int e = q * 256 + tid;
      if (e < EBF) {
        int kk = e / (BN / 4), n4 = e % (BN / 4);
        Bs[(n4 * 4 + 0) * 40 + kk] = f2b(bw[q].x);
        Bs[(n4 * 4 + 1) * 40 + kk] = f2b(bw[q].y);
        Bs[(n4 * 4 + 2) * 40 + kk] = f2b(bw[q].z);
        Bs[(n4 * 4 + 3) * 40 + kk] = f2b(bw[q].w);
      }
    }
    __syncthreads();
    bf16x8 af[FI], bfr[FJ];
#pragma unroll
    for (int i = 0; i < FI; i++)
      af[i] = *(const bf16x8*)&As[(wm + i * 16 + fm) * 40 + fq * 8];
#pragma unroll
    for (int j = 0; j < FJ; j++)
      bfr[j] = *(const bf16x8*)&Bs[(wn + j * 16 + fm) * 40 + fq * 8];
#pragma unroll
    for (int i = 0; i < FI; i++)
#pragma unroll
      for (int j = 0; j < FJ; j++)
        acc[i][j] = __builtin_amdgcn_mfma_f32_16x16x32_bf16(af[i], bfr[j], acc[i][j], 0, 0, 0);
  }
#pragma unroll
  for (int i = 0; i < FI; i++) {
#pragma unroll
    for (int j = 0; j < FJ; j++) {
      int r = m0 + wm + i * 16 + fq * 4;
      int ccol = n0 + wn + j * 16 + fm;
#pragma unroll
      for (int reg = 0; reg < 4; reg++)
        C[(size_t)(r + reg) * N + ccol] = acc[i][j][reg];
    }
  }
}

// s[h][n], t[h][n] via one wave per (node, head); shuffle reduce, no LDS.
__global__ void st_kernel(const float* __restrict__ h,
                          const float* __restrict__ asrc,
                          const float* __restrict__ adst,
                          float* __restrict__ s, float* __restrict__ t, int H) {
  int n = blockIdx.x;
  int wave = threadIdx.x >> 6, lane = threadIdx.x & 63;
  int HC = H * CDIM;
  float2 hv = *(const float2*)&h[(size_t)n * HC + wave * CDIM + lane * 2];
  float2 av = *(const float2*)&asrc[wave * CDIM + lane * 2];
  float2 dv = *(const float2*)&adst[wave * CDIM + lane * 2];
  float ps = hv.x * av.x + hv.y * av.y;
  float pt = hv.x * dv.x + hv.y * dv.y;
#pragma unroll
  for (int o = 32; o > 0; o >>= 1) {
    ps += __shfl_down(ps, o, 64);
    pt += __shfl_down(pt, o, 64);
  }
  if (lane == 0) {
    s[(size_t)wave * NNODE + n] = ps;
    t[(size_t)wave * NNODE + n] = pt;
  }
}

// Segmented rank sort, pass 1: partial rank counts over a 512-key segment.
// grid (16, SEG, H) = 512 blocks for H=4. Exact permutation.
__global__ __launch_bounds__(256) void rank_count_kernel(const float* __restrict__ s,
                                                         int* __restrict__ partial) {
  __shared__ __align__(16) float keys[SEGK];
  int hh = blockIdx.z, seg = blockIdx.y, tid = threadIdx.x;
  const float* sp = s + (size_t)hh * NNODE;
  for (int k = tid; k < SEGK; k += 256) keys[k] = sp[seg * SEGK + k];
  __syncthreads();
  int mi = blockIdx.x * 256 + tid;
  float mk = sp[mi];
  int jbase = seg * SEGK;
  int cnt = 0;
#pragma unroll 4
  for (int j = 0; j < SEGK; j += 4) {
    float4 kv = *(const float4*)&keys[j];
    int jj = jbase + j;
    cnt += (kv.x < mk) || (kv.x == mk && (jj + 0) < mi);
    cnt += (kv.y < mk) || (kv.y == mk && (jj + 1) < mi);
    cnt += (kv.z < mk) || (kv.z == mk && (jj + 2) < mi);
    cnt += (kv.w < mk) || (kv.w == mk && (jj + 3) < mi);
  }
  partial[((size_t)hh * SEG + seg) * NNODE + mi] = cnt;
}

// Pass 2: combine partials, scatter keys+indices to sorted position.
__global__ __launch_bounds__(256) void rank_scatter_kernel(const float* __restrict__ s,
                                                           const int* __restrict__ partial,
                                                           float* __restrict__ ss,
                                                           int* __restrict__ si) {
  int hh = blockIdx.y;
  int mi = blockIdx.x * 256 + threadIdx.x;
  int rank = 0;
#pragma unroll
  for (int g = 0; g < SEG; g++) rank += partial[((size_t)hh * SEG + g) * NNODE + mi];
  ss[(size_t)hh * NNODE + rank] = s[(size_t)hh * NNODE + mi];
  si[(size_t)hh * NNODE + rank] = mi;
}

// Pass A: per-chunk partial sums of e^{s}*h (P) and e^{0.2s}*h (M); z at 128.
__global__ __launch_bounds__(128) void passA_kernel(const float* __restrict__ h,
                                                    const float* __restrict__ ss,
                                                    const int* __restrict__ si,
                                                    float* __restrict__ partP,
                                                    float* __restrict__ partM, int H) {
  __shared__ float eP[CHUNK], eM[CHUNK];
  __shared__ int ids[CHUNK];
  int b = blockIdx.x, hh = b / NCHUNK, ci = b % NCHUNK;
  int c = threadIdx.x;
  int HC = H * CDIM;
  int base = ci * CHUNK;
  if (c < CHUNK) {
    float sv = ss[(size_t)hh * NNODE + base + c];
    ids[c] = si[(size_t)hh * NNODE + base + c];
    eP[c] = expf(sv);
    eM[c] = expf(NEG * sv);
  }
  __syncthreads();
  float sp = 0.f, sm = 0.f;
  for (int kb = 0; kb < CHUNK; kb += 8) {
    float v[8];
#pragma unroll
    for (int j = 0; j < 8; j++)
      v[j] = h[(size_t)ids[kb + j] * HC + hh * CDIM + c];
#pragma unroll
    for (int j = 0; j < 8; j++) {
      sp = fmaf(eP[kb + j], v[j], sp);
      sm = fmaf(eM[kb + j], v[j], sm);
    }
  }
  size_t o = ((size_t)hh * NCHUNK + ci) * TW;
  partP[o + c] = sp;
  partM[o + c] = sm;
  if (c == 0) {
    float zp = 0.f, zm = 0.f;
#pragma unroll
    for (int k = 0; k < CHUNK; k++) { zp += eP[k]; zm += eM[k]; }
    partP[o + 128] = zp;
    partM[o + 128] = zm;
  }
}

// Pass C with fused BATCHED carry combine (16 independent loads in flight).
// LDS-staged gather + dual scan, z at col 128.
__global__ __launch_bounds__(128) void passC_kernel(const float* __restrict__ h,
                                                    const float* __restrict__ ss,
                                                    const int* __restrict__ si,
                                                    const float* __restrict__ partP,
                                                    const float* __restrict__ partM,
                                                    float* __restrict__ SS,
                                                    float* __restrict__ PP, int H) {
  __shared__ float hrow[CHUNK][CDIM];  // 32 KB
  __shared__ float eP[CHUNK], eM[CHUNK];
  __shared__ int ids[CHUNK];
  int b = blockIdx.x, hh = b / NCHUNK, ci = b % NCHUNK;
  int c = threadIdx.x;
  int HC = H * CDIM;
  int base = ci * CHUNK;
  size_t hb = (size_t)hh * (NNODE + 1);
  if (c < CHUNK) {
    float sv = ss[(size_t)hh * NNODE + base + c];
    ids[c] = si[(size_t)hh * NNODE + base + c];
    eP[c] = expf(sv);
    eM[c] = expf(NEG * sv);
  }
  __syncthreads();
  // carry combine: feature columns (all threads), 16 loads in flight
  float cm = 0.f, cp = 0.f;
  for (int g0 = 0; g0 < NCHUNK; g0 += 16) {
    float vm[16], vp[16];
#pragma unroll
    for (int j = 0; j < 16; j++) {
      size_t o = ((size_t)hh * NCHUNK + g0 + j) * TW + c;
      vm[j] = partM[o];
      vp[j] = partP[o];
    }
#pragma unroll
    for (int j = 0; j < 16; j++) {
      if (g0 + j < ci) cm += vm[j];
      if (g0 + j > ci) cp += vp[j];
    }
  }
  // z carries (thread 0 only)
  float zcm = 0.f, zcp = 0.f;
  if (c == 0) {
    for (int g0 = 0; g0 < NCHUNK; g0 += 16) {
      float vm[16], vp[16];
#pragma unroll
      for (int j = 0; j < 16; j++) {
        size_t o = ((size_t)hh * NCHUNK + g0 + j) * TW + 128;
        vm[j] = partM[o];
        vp[j] = partP[o];
      }
#pragma unroll
      for (int j = 0; j < 16; j++) {
        if (g0 + j < ci) zcm += vm[j];
        if (g0 + j > ci) zcp += vp[j];
      }
    }
  }
  // gather h rows once into LDS (batched, per-thread column)
  for (int kb = 0; kb < CHUNK; kb += 8) {
    float v[8];
#pragma unroll
    for (int j = 0; j < 8; j++)
      v[j] = h[(size_t)ids[kb + j] * HC + hh * CDIM + c];
#pragma unroll
    for (int j = 0; j < 8; j++) hrow[kb + j][c] = v[j];
  }
  float runm = cm, runzm = zcm;
#pragma unroll 8
  for (int k = 0; k < CHUNK; k++) {
    size_t row = (hb + base + k) * TW;
    PP[row + c] = runm;
    if (c == 0) PP[row + 128] = runzm;
    runm = fmaf(eM[k], hrow[k][c], runm);
    runzm += eM[k];
  }
  if (ci == NCHUNK - 1) {
    size_t row = (hb + NNODE) * TW;
    PP[row + c] = runm;
    if (c == 0) PP[row + 128] = runzm;
  }
  float runp = cp, runzp = zcp;
#pragma unroll 8
  for (int k = CHUNK - 1; k >= 0; k--) {
    runp = fmaf(eP[k], hrow[k][c], runp);
    runzp += eP[k];
    size_t row = (hb + base + k) * TW;
    SS[row + c] = runp;
    if (c == 0) SS[row + 128] = runzp;
  }
  if (ci == NCHUNK - 1) {
    size_t row = (hb + NNODE) * TW;
    SS[row + c] = 0.f;
    if (c == 0) SS[row + 128] = 0.f;
  }
}

// Per (dest, head): binary search split point, combine tables, +bias, ELU.
template <typename OUT>
__global__ __launch_bounds__(128) void attend_kernel(const float* __restrict__ SS,
                                                     const float* __restrict__ PP,
                                                     const float* __restrict__ ss,
                                                     const float* __restrict__ tt,
                                                     const float* __restrict__ bias,
                                                     OUT* __restrict__ out, int H) {
  int b = blockIdx.x;
  int n = b / H, hh = b % H;
  int c = threadIdx.x;
  float tv = tt[(size_t)hh * NNODE + n];
  const float* sp = ss + (size_t)hh * NNODE;
  float thr = -tv;
  int lo = 0, hi = NNODE;
  while (lo < hi) { int mid = (lo + hi) >> 1; if (sp[mid] < thr) lo = mid + 1; else hi = mid; }
  size_t hb = (size_t)hh * (NNODE + 1);
  float wp = expf(tv), wm = expf(NEG * tv);
  float num = wp * SS[(hb + lo) * TW + c] + wm * PP[(hb + lo) * TW + c];
  float Z = wp * SS[(hb + lo) * TW + 128] + wm * PP[(hb + lo) * TW + 128];
  float o = num / Z + bias[hh * CDIM + c];
  float r = (o > 0.f) ? o : (expf(o) - 1.f);
  if constexpr (sizeof(OUT) == 2)
    out[(size_t)n * (H * CDIM) + hh * CDIM + c] = f2b(r);
  else
    out[(size_t)n * (H * CDIM) + hh * CDIM + c] = r;
}

__global__ __launch_bounds__(256) void mean_kernel(const float* __restrict__ x,
                                                   float* __restrict__ m) {
  __shared__ float red[256];
  int c = blockIdx.x, tid = threadIdx.x;
  float acc = 0.f;
  for (int i = tid; i < NNODE; i += 256) acc += x[(size_t)i * CDIM + c];
  red[tid] = acc; __syncthreads();
  for (int o = 128; o > 0; o >>= 1) { if (tid < o) red[tid] += red[tid + o]; __syncthreads(); }
  if (tid == 0) m[c] = red[0] * (1.f / NNODE);
}

__global__ __launch_bounds__(256) void fc_kernel(const float* __restrict__ m,
                                                 const float* __restrict__ fcW,
                                                 const float* __restrict__ fcb,
                                                 float* __restrict__ out) {
  int d = blockIdx.x * 256 + threadIdx.x;  // 768 total
  float acc = fcb[d];
  for (int c2 = 0; c2 < CDIM; c2++) acc = fmaf(m[c2], fcW[c2 * 768 + d], acc);
  out[d] = acc;
}

extern "C" void kernel_launch(void* const* d_in, const int* in_sizes, int n_in,
                              void* d_out, int out_size, void* d_ws, size_t ws_size,
                              hipStream_t stream) {
  const float* x   = (const float*)d_in[0];
  const float* W1  = (const float*)d_in[1];
  const float* as1 = (const float*)d_in[2];
  const float* ad1 = (const float*)d_in[3];
  const float* b1  = (const float*)d_in[4];
  const float* W2  = (const float*)d_in[5];
  const float* as2 = (const float*)d_in[6];
  const float* ad2 = (const float*)d_in[7];
  const float* b2  = (const float*)d_in[8];
  const float* fcW = (const float*)d_in[9];
  const float* fcb = (const float*)d_in[10];

  float* ws = (float*)d_ws;
  size_t off = 0;
  auto alloc = [&](size_t nfloats) { float* p = ws + off; off += nfloats; return p; };

  float* h1  = alloc((size_t)NNODE * 512);
  float* x2f = alloc((size_t)NNODE * 256);   // x2b bf16 [4096,512]
  float* h2  = alloc((size_t)NNODE * 128);
  float* x3  = alloc((size_t)NNODE * 128);
  float* s1  = alloc((size_t)4 * NNODE);
  float* t1  = alloc((size_t)4 * NNODE);
  float* sS1 = alloc((size_t)4 * NNODE);
  int*   sI1 = (int*)alloc((size_t)4 * NNODE);
  float* SS1 = alloc((size_t)4 * (NNODE + 1) * TW);
  float* PP1 = alloc((size_t)4 * (NNODE + 1) * TW);
  float* pP1 = alloc((size_t)4 * NCHUNK * TW);
  float* pM1 = alloc((size_t)4 * NCHUNK * TW);
  float* s2  = alloc(NNODE);
  float* t2  = alloc(NNODE);
  float* sS2 = alloc(NNODE);
  int*   sI2 = (int*)alloc(NNODE);
  float* SS2 = alloc((size_t)(NNODE + 1) * TW);
  float* PP2 = alloc((size_t)(NNODE + 1) * TW);
  float* pP2 = alloc((size_t)NCHUNK * TW);
  float* pM2 = alloc((size_t)NCHUNK * TW);
  float* mv  = alloc(128);
  int*   rparts = (int*)alloc((size_t)4 * SEG * NNODE);

  unsigned short* x2b = (unsigned short*)x2f;

  // Layer 1: GEMM converts x (fp32) and W1 (fp32, [K,N]) on the fly
  mfma_gemm<64, 64, false><<<dim3(512 / 64, NNODE / 64), 256, 0, stream>>>(x, W1, h1, NNODE, 512, 768);
  st_kernel<<<NNODE, 4 * 64, 0, stream>>>(h1, as1, ad1, s1, t1, 4);
  rank_count_kernel<<<dim3(NNODE / 256, SEG, 4), 256, 0, stream>>>(s1, rparts);
  rank_scatter_kernel<<<dim3(NNODE / 256, 4), 256, 0, stream>>>(s1, rparts, sS1, sI1);
  passA_kernel<<<4 * NCHUNK, 128, 0, stream>>>(h1, sS1, sI1, pP1, pM1, 4);
  passC_kernel<<<4 * NCHUNK, 128, 0, stream>>>(h1, sS1, sI1, pP1, pM1, SS1, PP1, 4);
  attend_kernel<unsigned short><<<NNODE * 4, 128, 0, stream>>>(SS1, PP1, sS1, t1, b1, x2b, 4);
  // Layer 2: A = x2b bf16, B = W2 fp32 [512,128] converted on the fly
  mfma_gemm<32, 64, true><<<dim3(128 / 64, NNODE / 32), 256, 0, stream>>>(x2b, W2, h2, NNODE, 128, 512);
  st_kernel<<<NNODE, 1 * 64, 0, stream>>>(h2, as2, ad2, s2, t2, 1);
  rank_count_kernel<<<dim3(NNODE / 256, SEG, 1), 256, 0, stream>>>(s2, rparts);
  rank_scatter_kernel<<<dim3(NNODE / 256, 1), 256, 0, stream>>>(s2, rparts, sS2, sI2);
  passA_kernel<<<NCHUNK, 128, 0, stream>>>(h2, sS2, sI2, pP2, pM2, 1);
  passC_kernel<<<NCHUNK, 128, 0, stream>>>(h2, sS2, sI2, pP2, pM2, SS2, PP2, 1);
  attend_kernel<float><<<NNODE, 128, 0, stream>>>(SS2, PP2, sS2, t2, b2, x3, 1);
  // Readout
  mean_kernel<<<128, 256, 0, stream>>>(x3, mv);
  fc_kernel<<<3, 256, 0, stream>>>(mv, fcW, fcb, (float*)d_out);
}

// Round 11
// 224.853 us; speedup vs baseline: 5.2639x; 1.1256x over previous
//
#include <hip/hip_runtime.h>
#include <hip/hip_bf16.h>

// FacePartGAT: dense-graph GATConv x2 + mean + fc on MI355X. ALL I/O fp32.
// e[i,j] = leaky_relu(t_i + s_j) => softmax aggregation factorizes after
// sorting sources by s_j (prefix/suffix tables + binary search). Exact.
// Round 11: best-of-each-phase recombination + GEMM K-loop register prefetch.
//  - prep restored (r10's on-the-fly fp32 conversion: FETCH 13->50MB,
//    LDS conflicts 0.79M->6.7M — falsified)
//  - GEMM: bf16 K-contig operands + prefetch next tile's registers before
//    the MFMA section (overlap global latency with compute)
//  - segmented sort (r7), fused batched passC carry (r10)

#define NNODE 4096
#define CDIM 128
#define TW 132           // table width: 128 features + z at col 128
#define NEG 0.2f
#define CHUNK 64
#define NCHUNK 64        // NNODE / CHUNK
#define SEG 8
#define SEGK (NNODE / SEG)  // 512

typedef __bf16 bf16x8 __attribute__((ext_vector_type(8)));
typedef float f32x4 __attribute__((ext_vector_type(4)));

__device__ __forceinline__ unsigned short f2b(float f) {
  unsigned int u = __float_as_uint(f);
  u += 0x7fffu + ((u >> 16) & 1u);  // RTNE
  return (unsigned short)(u >> 16);
}

// One kernel: [0,3072) convert x -> bf16; [3072,3168) transpose W1; rest W2.
__global__ __launch_bounds__(256) void prep_kernel(const float* __restrict__ x,
                                                   const float* __restrict__ W1,
                                                   const float* __restrict__ W2,
                                                   unsigned short* __restrict__ xb,
                                                   unsigned short* __restrict__ W1t,
                                                   unsigned short* __restrict__ W2t) {
  __shared__ float tile[64][65];
  int b = blockIdx.x, t = threadIdx.x;
  if (b < 3072) {  // convert x: 4096*768/4 quads
    int i = b * 256 + t;
    float4 v = ((const float4*)x)[i];
    ushort4 o;
    o.x = f2b(v.x); o.y = f2b(v.y); o.z = f2b(v.z); o.w = f2b(v.w);
    ((ushort4*)xb)[i] = o;
    return;
  }
  const float* W; unsigned short* Wt; int K, N, n0, k0;
  if (b < 3072 + 96) {  // W1 [768,512] -> W1t [512,768]
    int b2 = b - 3072; W = W1; Wt = W1t; K = 768; N = 512;
    n0 = (b2 & 7) * 64; k0 = (b2 >> 3) * 64;
  } else {              // W2 [512,128] -> W2t [128,512]
    int b3 = b - 3072 - 96; W = W2; Wt = W2t; K = 512; N = 128;
    n0 = (b3 & 1) * 64; k0 = (b3 >> 1) * 64;
  }
  for (int p = 0; p < 16; p++) {
    int e = p * 256 + t;
    int rr = e >> 6, cc = e & 63;
    tile[rr][cc] = W[(size_t)(k0 + rr) * N + n0 + cc];
  }
  __syncthreads();
  for (int p = 0; p < 16; p++) {
    int e = p * 256 + t;
    int rr = e >> 6, cc = e & 63;  // rr: n-dir, cc: k-dir
    Wt[(size_t)(n0 + rr) * K + k0 + cc] = f2b(tile[cc][rr]);
  }
}

// C[M,N] = A[M,K] x Bt[N,K]^T, both bf16 K-contig. BK=32, 256 thr = 4 waves
// (2x2). Register prefetch: tile k+1 global loads issued between the LDS
// barrier and the MFMA section so global latency overlaps compute.
template <int BM, int BN>
__global__ __launch_bounds__(256) void mfma_gemm_bt(const unsigned short* __restrict__ A,
                                                    const unsigned short* __restrict__ Bt,
                                                    float* __restrict__ C,
                                                    int M, int N, int K) {
  __shared__ __align__(16) unsigned short As[BM * 40];
  __shared__ __align__(16) unsigned short Bs[BN * 40];
  constexpr int WM = BM / 2, WN = BN / 2;
  constexpr int FI = WM / 16, FJ = WN / 16;
  constexpr int EA = BM * 32 / 8;
  constexpr int EB = BN * 32 / 8;
  constexpr int NA = (EA + 255) / 256;
  constexpr int NB = (EB + 255) / 256;
  int tid = threadIdx.x;
  int lane = tid & 63, wave = tid >> 6;
  int wm = (wave >> 1) * WM, wn = (wave & 1) * WN;
  int m0 = blockIdx.y * BM, n0 = blockIdx.x * BN;
  int fm = lane & 15, fq = lane >> 4;
  f32x4 acc[FI][FJ] = {};
  uint4 ar[NA], br[NB];
  // preload tile 0
#pragma unroll
  for (int q = 0; q < NA; q++) {
    int e = q * 256 + tid;
    if (e < EA) {
      int r = e >> 2, kk = (e & 3) * 8;
      ar[q] = *(const uint4*)(A + (size_t)(m0 + r) * K + kk);
    }
  }
#pragma unroll
  for (int q = 0; q < NB; q++) {
    int e = q * 256 + tid;
    if (e < EB) {
      int r = e >> 2, kk = (e & 3) * 8;
      br[q] = *(const uint4*)(Bt + (size_t)(n0 + r) * K + kk);
    }
  }
  for (int k0 = 0; k0 < K; k0 += 32) {
    __syncthreads();  // previous iter's ds_reads done before overwrite
#pragma unroll
    for (int q = 0; q < NA; q++) {
      int e = q * 256 + tid;
      if (e < EA) {
        int r = e >> 2, kk = (e & 3) * 8;
        *(uint4*)&As[r * 40 + kk] = ar[q];
      }
    }
#pragma unroll
    for (int q = 0; q < NB; q++) {
      int e = q * 256 + tid;
      if (e < EB) {
        int r = e >> 2, kk = (e & 3) * 8;
        *(uint4*)&Bs[r * 40 + kk] = br[q];
      }
    }
    __syncthreads();
    // prefetch tile k+1 (in flight during ds_read + MFMA below)
    if (k0 + 32 < K) {
#pragma unroll
      for (int q = 0; q < NA; q++) {
        int e = q * 256 + tid;
        if (e < EA) {
          int r = e >> 2, kk = (e & 3) * 8;
          ar[q] = *(const uint4*)(A + (size_t)(m0 + r) * K + k0 + 32 + kk);
        }
      }
#pragma unroll
      for (int q = 0; q < NB; q++) {
        int e = q * 256 + tid;
        if (e < EB) {
          int r = e >> 2, kk = (e & 3) * 8;
          br[q] = *(const uint4*)(Bt + (size_t)(n0 + r) * K + k0 + 32 + kk);
        }
      }
    }
    bf16x8 af[FI], bfr[FJ];
#pragma unroll
    for (int i = 0; i < FI; i++)
      af[i] = *(const bf16x8*)&As[(wm + i * 16 + fm) * 40 + fq * 8];
#pragma unroll
    for (int j = 0; j < FJ; j++)
      bfr[j] = *(const bf16x8*)&Bs[(wn + j * 16 + fm) * 40 + fq * 8];
#pragma unroll
    for (int i = 0; i < FI; i++)
#pragma unroll
      for (int j = 0; j < FJ; j++)
        acc[i][j] = __builtin_amdgcn_mfma_f32_16x16x32_bf16(af[i], bfr[j], acc[i][j], 0, 0, 0);
  }
#pragma unroll
  for (int i = 0; i < FI; i++) {
#pragma unroll
    for (int j = 0; j < FJ; j++) {
      int r = m0 + wm + i * 16 + fq * 4;
      int ccol = n0 + wn + j * 16 + fm;
#pragma unroll
      for (int reg = 0; reg < 4; reg++)
        C[(size_t)(r + reg) * N + ccol] = acc[i][j][reg];
    }
  }
}

// s[h][n], t[h][n] via one wave per (node, head); shuffle reduce, no LDS.
__global__ void st_kernel(const float* __restrict__ h,
                          const float* __restrict__ asrc,
                          const float* __restrict__ adst,
                          float* __restrict__ s, float* __restrict__ t, int H) {
  int n = blockIdx.x;
  int wave = threadIdx.x >> 6, lane = threadIdx.x & 63;
  int HC = H * CDIM;
  float2 hv = *(const float2*)&h[(size_t)n * HC + wave * CDIM + lane * 2];
  float2 av = *(const float2*)&asrc[wave * CDIM + lane * 2];
  float2 dv = *(const float2*)&adst[wave * CDIM + lane * 2];
  float ps = hv.x * av.x + hv.y * av.y;
  float pt = hv.x * dv.x + hv.y * dv.y;
#pragma unroll
  for (int o = 32; o > 0; o >>= 1) {
    ps += __shfl_down(ps, o, 64);
    pt += __shfl_down(pt, o, 64);
  }
  if (lane == 0) {
    s[(size_t)wave * NNODE + n] = ps;
    t[(size_t)wave * NNODE + n] = pt;
  }
}

// Segmented rank sort, pass 1: partial rank counts over a 512-key segment.
__global__ __launch_bounds__(256) void rank_count_kernel(const float* __restrict__ s,
                                                         int* __restrict__ partial) {
  __shared__ __align__(16) float keys[SEGK];
  int hh = blockIdx.z, seg = blockIdx.y, tid = threadIdx.x;
  const float* sp = s + (size_t)hh * NNODE;
  for (int k = tid; k < SEGK; k += 256) keys[k] = sp[seg * SEGK + k];
  __syncthreads();
  int mi = blockIdx.x * 256 + tid;
  float mk = sp[mi];
  int jbase = seg * SEGK;
  int cnt = 0;
#pragma unroll 4
  for (int j = 0; j < SEGK; j += 4) {
    float4 kv = *(const float4*)&keys[j];
    int jj = jbase + j;
    cnt += (kv.x < mk) || (kv.x == mk && (jj + 0) < mi);
    cnt += (kv.y < mk) || (kv.y == mk && (jj + 1) < mi);
    cnt += (kv.z < mk) || (kv.z == mk && (jj + 2) < mi);
    cnt += (kv.w < mk) || (kv.w == mk && (jj + 3) < mi);
  }
  partial[((size_t)hh * SEG + seg) * NNODE + mi] = cnt;
}

// Pass 2: combine partials, scatter keys+indices to sorted position.
__global__ __launch_bounds__(256) void rank_scatter_kernel(const float* __restrict__ s,
                                                           const int* __restrict__ partial,
                                                           float* __restrict__ ss,
                                                           int* __restrict__ si) {
  int hh = blockIdx.y;
  int mi = blockIdx.x * 256 + threadIdx.x;
  int rank = 0;
#pragma unroll
  for (int g = 0; g < SEG; g++) rank += partial[((size_t)hh * SEG + g) * NNODE + mi];
  ss[(size_t)hh * NNODE + rank] = s[(size_t)hh * NNODE + mi];
  si[(size_t)hh * NNODE + rank] = mi;
}

// Pass A: per-chunk partial sums of e^{s}*h (P) and e^{0.2s}*h (M); z at 128.
__global__ __launch_bounds__(128) void passA_kernel(const float* __restrict__ h,
                                                    const float* __restrict__ ss,
                                                    const int* __restrict__ si,
                                                    float* __restrict__ partP,
                                                    float* __restrict__ partM, int H) {
  __shared__ float eP[CHUNK], eM[CHUNK];
  __shared__ int ids[CHUNK];
  int b = blockIdx.x, hh = b / NCHUNK, ci = b % NCHUNK;
  int c = threadIdx.x;
  int HC = H * CDIM;
  int base = ci * CHUNK;
  if (c < CHUNK) {
    float sv = ss[(size_t)hh * NNODE + base + c];
    ids[c] = si[(size_t)hh * NNODE + base + c];
    eP[c] = expf(sv);
    eM[c] = expf(NEG * sv);
  }
  __syncthreads();
  float sp = 0.f, sm = 0.f;
  for (int kb = 0; kb < CHUNK; kb += 8) {
    float v[8];
#pragma unroll
    for (int j = 0; j < 8; j++)
      v[j] = h[(size_t)ids[kb + j] * HC + hh * CDIM + c];
#pragma unroll
    for (int j = 0; j < 8; j++) {
      sp = fmaf(eP[kb + j], v[j], sp);
      sm = fmaf(eM[kb + j], v[j], sm);
    }
  }
  size_t o = ((size_t)hh * NCHUNK + ci) * TW;
  partP[o + c] = sp;
  partM[o + c] = sm;
  if (c == 0) {
    float zp = 0.f, zm = 0.f;
#pragma unroll
    for (int k = 0; k < CHUNK; k++) { zp += eP[k]; zm += eM[k]; }
    partP[o + 128] = zp;
    partM[o + 128] = zm;
  }
}

// Pass C with fused BATCHED carry combine (16 independent loads in flight).
// LDS-staged gather + dual scan, z at col 128.
__global__ __launch_bounds__(128) void passC_kernel(const float* __restrict__ h,
                                                    const float* __restrict__ ss,
                                                    const int* __restrict__ si,
                                                    const float* __restrict__ partP,
                                                    const float* __restrict__ partM,
                                                    float* __restrict__ SS,
                                                    float* __restrict__ PP, int H) {
  __shared__ float hrow[CHUNK][CDIM];  // 32 KB
  __shared__ float eP[CHUNK], eM[CHUNK];
  __shared__ int ids[CHUNK];
  int b = blockIdx.x, hh = b / NCHUNK, ci = b % NCHUNK;
  int c = threadIdx.x;
  int HC = H * CDIM;
  int base = ci * CHUNK;
  size_t hb = (size_t)hh * (NNODE + 1);
  if (c < CHUNK) {
    float sv = ss[(size_t)hh * NNODE + base + c];
    ids[c] = si[(size_t)hh * NNODE + base + c];
    eP[c] = expf(sv);
    eM[c] = expf(NEG * sv);
  }
  __syncthreads();
  // carry combine: feature columns (all threads), 16 loads in flight
  float cm = 0.f, cp = 0.f;
  for (int g0 = 0; g0 < NCHUNK; g0 += 16) {
    float vm[16], vp[16];
#pragma unroll
    for (int j = 0; j < 16; j++) {
      size_t o = ((size_t)hh * NCHUNK + g0 + j) * TW + c;
      vm[j] = partM[o];
      vp[j] = partP[o];
    }
#pragma unroll
    for (int j = 0; j < 16; j++) {
      if (g0 + j < ci) cm += vm[j];
      if (g0 + j > ci) cp += vp[j];
    }
  }
  // z carries (thread 0 only)
  float zcm = 0.f, zcp = 0.f;
  if (c == 0) {
    for (int g0 = 0; g0 < NCHUNK; g0 += 16) {
      float vm[16], vp[16];
#pragma unroll
      for (int j = 0; j < 16; j++) {
        size_t o = ((size_t)hh * NCHUNK + g0 + j) * TW + 128;
        vm[j] = partM[o];
        vp[j] = partP[o];
      }
#pragma unroll
      for (int j = 0; j < 16; j++) {
        if (g0 + j < ci) zcm += vm[j];
        if (g0 + j > ci) zcp += vp[j];
      }
    }
  }
  // gather h rows once into LDS (batched, per-thread column)
  for (int kb = 0; kb < CHUNK; kb += 8) {
    float v[8];
#pragma unroll
    for (int j = 0; j < 8; j++)
      v[j] = h[(size_t)ids[kb + j] * HC + hh * CDIM + c];
#pragma unroll
    for (int j = 0; j < 8; j++) hrow[kb + j][c] = v[j];
  }
  float runm = cm, runzm = zcm;
#pragma unroll 8
  for (int k = 0; k < CHUNK; k++) {
    size_t row = (hb + base + k) * TW;
    PP[row + c] = runm;
    if (c == 0) PP[row + 128] = runzm;
    runm = fmaf(eM[k], hrow[k][c], runm);
    runzm += eM[k];
  }
  if (ci == NCHUNK - 1) {
    size_t row = (hb + NNODE) * TW;
    PP[row + c] = runm;
    if (c == 0) PP[row + 128] = runzm;
  }
  float runp = cp, runzp = zcp;
#pragma unroll 8
  for (int k = CHUNK - 1; k >= 0; k--) {
    runp = fmaf(eP[k], hrow[k][c], runp);
    runzp += eP[k];
    size_t row = (hb + base + k) * TW;
    SS[row + c] = runp;
    if (c == 0) SS[row + 128] = runzp;
  }
  if (ci == NCHUNK - 1) {
    size_t row = (hb + NNODE) * TW;
    SS[row + c] = 0.f;
    if (c == 0) SS[row + 128] = 0.f;
  }
}

// Per (dest, head): binary search split point, combine tables, +bias, ELU.
template <typename OUT>
__global__ __launch_bounds__(128) void attend_kernel(const float* __restrict__ SS,
                                                     const float* __restrict__ PP,
                                                     const float* __restrict__ ss,
                                                     const float* __restrict__ tt,
                                                     const float* __restrict__ bias,
                                                     OUT* __restrict__ out, int H) {
  int b = blockIdx.x;
  int n = b / H, hh = b % H;
  int c = threadIdx.x;
  float tv = tt[(size_t)hh * NNODE + n];
  const float* sp = ss + (size_t)hh * NNODE;
  float thr = -tv;
  int lo = 0, hi = NNODE;
  while (lo < hi) { int mid = (lo + hi) >> 1; if (sp[mid] < thr) lo = mid + 1; else hi = mid; }
  size_t hb = (size_t)hh * (NNODE + 1);
  float wp = expf(tv), wm = expf(NEG * tv);
  float num = wp * SS[(hb + lo) * TW + c] + wm * PP[(hb + lo) * TW + c];
  float Z = wp * SS[(hb + lo) * TW + 128] + wm * PP[(hb + lo) * TW + 128];
  float o = num / Z + bias[hh * CDIM + c];
  float r = (o > 0.f) ? o : (expf(o) - 1.f);
  if constexpr (sizeof(OUT) == 2)
    out[(size_t)n * (H * CDIM) + hh * CDIM + c] = f2b(r);
  else
    out[(size_t)n * (H * CDIM) + hh * CDIM + c] = r;
}

__global__ __launch_bounds__(256) void mean_kernel(const float* __restrict__ x,
                                                   float* __restrict__ m) {
  __shared__ float red[256];
  int c = blockIdx.x, tid = threadIdx.x;
  float acc = 0.f;
  for (int i = tid; i < NNODE; i += 256) acc += x[(size_t)i * CDIM + c];
  red[tid] = acc; __syncthreads();
  for (int o = 128; o > 0; o >>= 1) { if (tid < o) red[tid] += red[tid + o]; __syncthreads(); }
  if (tid == 0) m[c] = red[0] * (1.f / NNODE);
}

__global__ __launch_bounds__(256) void fc_kernel(const float* __restrict__ m,
                                                 const float* __restrict__ fcW,
                                                 const float* __restrict__ fcb,
                                                 float* __restrict__ out) {
  int d = blockIdx.x * 256 + threadIdx.x;  // 768 total
  float acc = fcb[d];
  for (int c2 = 0; c2 < CDIM; c2++) acc = fmaf(m[c2], fcW[c2 * 768 + d], acc);
  out[d] = acc;
}

extern "C" void kernel_launch(void* const* d_in, const int* in_sizes, int n_in,
                              void* d_out, int out_size, void* d_ws, size_t ws_size,
                              hipStream_t stream) {
  const float* x   = (const float*)d_in[0];
  const float* W1  = (const float*)d_in[1];
  const float* as1 = (const float*)d_in[2];
  const float* ad1 = (const float*)d_in[3];
  const float* b1  = (const float*)d_in[4];
  const float* W2  = (const float*)d_in[5];
  const float* as2 = (const float*)d_in[6];
  const float* ad2 = (const float*)d_in[7];
  const float* b2  = (const float*)d_in[8];
  const float* fcW = (const float*)d_in[9];
  const float* fcb = (const float*)d_in[10];

  float* ws = (float*)d_ws;
  size_t off = 0;
  auto alloc = [&](size_t nfloats) { float* p = ws + off; off += nfloats; return p; };

  float* h1  = alloc((size_t)NNODE * 512);
  float* x2f = alloc((size_t)NNODE * 256 + 64 + 16384);  // x2b bf16 + W2t bf16
  float* h2  = alloc((size_t)NNODE * 128);
  float* x3  = alloc((size_t)NNODE * 128);
  float* s1  = alloc((size_t)4 * NNODE);
  float* t1  = alloc((size_t)4 * NNODE);
  float* sS1 = alloc((size_t)4 * NNODE);
  int*   sI1 = (int*)alloc((size_t)4 * NNODE);
  float* SS1 = alloc((size_t)4 * (NNODE + 1) * TW);
  float* PP1 = alloc((size_t)4 * (NNODE + 1) * TW);
  float* pP1 = alloc((size_t)4 * NCHUNK * TW);
  float* pM1 = alloc((size_t)4 * NCHUNK * TW);
  float* s2  = alloc(NNODE);
  float* t2  = alloc(NNODE);
  float* sS2 = alloc(NNODE);
  int*   sI2 = (int*)alloc(NNODE);
  float* SS2 = alloc((size_t)(NNODE + 1) * TW);
  float* PP2 = alloc((size_t)(NNODE + 1) * TW);
  float* pP2 = alloc((size_t)NCHUNK * TW);
  float* pM2 = alloc((size_t)NCHUNK * TW);
  float* mv  = alloc(128);
  int*   rparts = (int*)alloc((size_t)4 * SEG * NNODE);

  // bf16 staging aliased into PP1/SS1 (first written by passC1, strictly after
  // gemm1 last reads them — stream ordered).
  unsigned short* xb  = (unsigned short*)PP1;  // 4096x768 bf16 = 6.3 MB (< 8.65 MB)
  unsigned short* W1t = (unsigned short*)SS1;  // 512x768 bf16
  unsigned short* x2b = (unsigned short*)x2f;                       // 4096x512 bf16
  unsigned short* W2t = (unsigned short*)(x2f + NNODE * 256 + 64);  // 128x512 bf16

  // Prep: convert x + transpose/cast W1, W2 (one kernel)
  prep_kernel<<<3072 + 96 + 16, 256, 0, stream>>>(x, W1, W2, xb, W1t, W2t);
  // Layer 1  (64x64 tiles -> 512 blocks, 2 blocks/CU, prefetched K-loop)
  mfma_gemm_bt<64, 64><<<dim3(512 / 64, NNODE / 64), 256, 0, stream>>>(xb, W1t, h1, NNODE, 512, 768);
  st_kernel<<<NNODE, 4 * 64, 0, stream>>>(h1, as1, ad1, s1, t1, 4);
  rank_count_kernel<<<dim3(NNODE / 256, SEG, 4), 256, 0, stream>>>(s1, rparts);
  rank_scatter_kernel<<<dim3(NNODE / 256, 4), 256, 0, stream>>>(s1, rparts, sS1, sI1);
  passA_kernel<<<4 * NCHUNK, 128, 0, stream>>>(h1, sS1, sI1, pP1, pM1, 4);
  passC_kernel<<<4 * NCHUNK, 128, 0, stream>>>(h1, sS1, sI1, pP1, pM1, SS1, PP1, 4);
  attend_kernel<unsigned short><<<NNODE * 4, 128, 0, stream>>>(SS1, PP1, sS1, t1, b1, x2b, 4);
  // Layer 2  (32x64 tiles -> 256 blocks)
  mfma_gemm_bt<32, 64><<<dim3(128 / 64, NNODE / 32), 256, 0, stream>>>(x2b, W2t, h2, NNODE, 128, 512);
  st_kernel<<<NNODE, 1 * 64, 0, stream>>>(h2, as2, ad2, s2, t2, 1);
  rank_count_kernel<<<dim3(NNODE / 256, SEG, 1), 256, 0, stream>>>(s2, rparts);
  rank_scatter_kernel<<<dim3(NNODE / 256, 1), 256, 0, stream>>>(s2, rparts, sS2, sI2);
  passA_kernel<<<NCHUNK, 128, 0, stream>>>(h2, sS2, sI2, pP2, pM2, 1);
  passC_kernel<<<NCHUNK, 128, 0, stream>>>(h2, sS2, sI2, pP2, pM2, SS2, PP2, 1);
  attend_kernel<float><<<NNODE, 128, 0, stream>>>(SS2, PP2, sS2, t2, b2, x3, 1);
  // Readout
  mean_kernel<<<128, 256, 0, stream>>>(x3, mv);
  fc_kernel<<<3, 256, 0, stream>>>(mv, fcW, fcb, (float*)d_out);
}